// Round 7
// baseline (235.622 us; speedup 1.0000x reference)
//
#include <hip/hip_runtime.h>

typedef _Float16 f16;
typedef _Float16 f16x8 __attribute__((ext_vector_type(8)));
typedef float f32x4 __attribute__((ext_vector_type(4)));

#define IN_DIM  8192
#define OUT_DIM 8192
#define BATCH   256
#define BK      32
#define BN      128
#define NSPLIT  4
#define KSPL    (IN_DIM / NSPLIT)   /* 2048 per split */
#define NSTEP   (KSPL / BK)         /* 64 K-steps */

__device__ __forceinline__ float softplus_f(float r) {
    return __logf(1.0f + __expf(r));
}

// ---- W staging (threads 512..1023): one set = 6 x f32x4 = 24 VGPRs ----
#define ISSUE_W(S, Ma,Mb,Ra,Rb,Ea,Eb) do {                                   \
    const int o_ = (S) * BK;                                                 \
    Ma = *(const f32x4*)(mup + o_);   Mb = *(const f32x4*)(mup + o_ + 4);    \
    Ra = *(const f32x4*)(rhp + o_);   Rb = *(const f32x4*)(rhp + o_ + 4);    \
    Ea = *(const f32x4*)(epp + o_);   Eb = *(const f32x4*)(epp + o_ + 4);    \
} while (0)

#define COMMIT_W(BUF, Ma,Mb,Ra,Rb,Ea,Eb) do {                                \
    f16x8 wv_;                                                               \
    _Pragma("unroll")                                                        \
    for (int q_ = 0; q_ < 4; ++q_) {                                         \
        wv_[q_]   = (f16)(Ma[q_] + softplus_f(Ra[q_]) * Ea[q_]);             \
        wv_[4+q_] = (f16)(Mb[q_] + softplus_f(Rb[q_]) * Eb[q_]);             \
    }                                                                        \
    *(f16x8*)&smW[BUF][wst] = wv_;                                           \
} while (0)

// ---- A staging (threads 0..511): single set, depth covered by 4-wave TLP
//      + L2-resident x. f16 mode: raw 32B copy, no VALU at all.
#define ISSUE_A(S) do {                                                      \
    if constexpr (XF16) {                                                    \
        Xa = *(const f16x8*)(xap + (S) * BK);                                \
        Xb = *(const f16x8*)(xap + (S) * BK + 8);                            \
    } else {                                                                 \
        F0 = *(const f32x4*)(xfp + (S) * BK);                                \
        F1 = *(const f32x4*)(xfp + (S) * BK + 4);                            \
        F2 = *(const f32x4*)(xfp + (S) * BK + 8);                            \
        F3 = *(const f32x4*)(xfp + (S) * BK + 12);                           \
    }                                                                        \
} while (0)

#define COMMIT_A(BUF) do {                                                   \
    f16x8 a0_, a1_;                                                          \
    if constexpr (XF16) {                                                    \
        a0_ = Xa; a1_ = Xb;                                                  \
    } else {                                                                 \
        _Pragma("unroll")                                                    \
        for (int q_ = 0; q_ < 4; ++q_) {                                     \
            a0_[q_] = (f16)F0[q_];  a0_[4+q_] = (f16)F1[q_];                 \
            a1_[q_] = (f16)F2[q_];  a1_[4+q_] = (f16)F3[q_];                 \
        }                                                                    \
    }                                                                        \
    *(f16x8*)&smA[BUF][ast0] = a0_;                                          \
    *(f16x8*)&smA[BUF][ast1] = a1_;                                          \
} while (0)

// One K-step: per wave 4x2 fragments of 16x16x32 f16 (64x32 sub-tile).
// Proven 0-conflict swizzle (ko ^ ((row>>1)&3)).
#define MSTEP(B) do {                                                        \
    const int rr_ = lane & 15;                                               \
    const int ko_ = lane >> 4;                                               \
    f16x8 bf_[2];                                                            \
    _Pragma("unroll")                                                        \
    for (int j_ = 0; j_ < 2; ++j_) {                                         \
        const int br_ = wn * 32 + j_ * 16 + rr_;                             \
        bf_[j_] = *(const f16x8*)&smW[B][br_ * BK + ((ko_ ^ ((br_ >> 1) & 3)) << 3)]; \
    }                                                                        \
    _Pragma("unroll")                                                        \
    for (int i_ = 0; i_ < 4; ++i_) {                                         \
        const int ar_ = wm * 64 + i_ * 16 + rr_;                             \
        const f16x8 af_ = *(const f16x8*)&smA[B][ar_ * BK + ((ko_ ^ ((ar_ >> 1) & 3)) << 3)]; \
        _Pragma("unroll")                                                    \
        for (int j_ = 0; j_ < 2; ++j_)                                       \
            acc[i_][j_] = __builtin_amdgcn_mfma_f32_16x16x32_f16(            \
                af_, bf_[j_], acc[i_][j_], 0, 0, 0);                         \
    }                                                                        \
} while (0)

// Barrier draining only LDS ops; global loads stay in flight across it.
#define BARRIER() do {                                                       \
    asm volatile("s_waitcnt lgkmcnt(0)" ::: "memory");                       \
    __builtin_amdgcn_s_barrier();                                            \
} while (0)

template <bool XF16>
__global__ __launch_bounds__(1024, 4)
void vl_main(const float* __restrict__ x,
             const f16*   __restrict__ x16,
             const float* __restrict__ muw,
             const float* __restrict__ rhow,
             const float* __restrict__ epsw,
             const float* __restrict__ mub,
             const float* __restrict__ rhob,
             const float* __restrict__ epsb,
             float* __restrict__ out)
{
    // A [2][256][32] f16 = 32 KiB + W [2][128][32] f16 = 16 KiB -> 48 KiB.
    // 16 waves/block, 1 block/CU -> 4 waves/SIMD at 128-reg cap; acc=32
    // keeps every branch under the cap (no R2-style spill, no R3 strangle).
    __shared__ __align__(16) f16 smA[2][BATCH * BK];
    __shared__ __align__(16) f16 smW[2][BN * BK];

    const int t    = threadIdx.x;
    const int lane = t & 63;
    const int wid  = t >> 6;     // 0..15
    const int wm   = wid >> 2;   // 0..3 : rows [wm*64, +64)
    const int wn   = wid & 3;    // 0..3 : cols [wn*32, +32)

    // XCD-aware mapping: an XCD pair owns one k-split (x chunk L2-resident).
    const int bx = blockIdx.x;
    const int x7 = bx & 7;
    const int sk = x7 >> 1;                      // 0..3 k-split
    const int nb = (x7 & 1) * 32 + (bx >> 3);    // 0..63 n-block
    const int k_base = sk * KSPL;
    const int n_base = nb * BN;

    const bool isA = (t < 512);

    // ---- A map (t<512): row = t>>1 (0..255), half = t&1 (16 f16 = 32 B) ----
    const int arow = (t & 511) >> 1;
    const int ahalf = t & 1;
    const f16*   xap = x16 + (size_t)arow * IN_DIM + k_base + ahalf * 16;
    const float* xfp = x   + (size_t)arow * IN_DIM + k_base + ahalf * 16;
    const int aswr = (arow >> 1) & 3;
    const int ast0 = arow * BK + (((ahalf * 2 + 0) ^ aswr) << 3);
    const int ast1 = arow * BK + (((ahalf * 2 + 1) ^ aswr) << 3);

    // ---- W map (t>=512): row = u>>2 (0..127), slot = u&3 (8 f32 = 32 B) ----
    const int u = t & 511;
    const int wrow = u >> 2;
    const int wslot = u & 3;
    const size_t woff = (size_t)(n_base + wrow) * IN_DIM + k_base + wslot * 8;
    const float* mup = muw  + woff;
    const float* rhp = rhow + woff;
    const float* epp = epsw + woff;
    const int wst = wrow * BK + ((wslot ^ ((wrow >> 1) & 3)) << 3);

    f32x4 acc[4][2];
#pragma unroll
    for (int i = 0; i < 4; ++i)
#pragma unroll
        for (int j = 0; j < 2; ++j)
            acc[i][j] = (f32x4){0.f, 0.f, 0.f, 0.f};

    // Named register sets (static indexing -> no scratch, rule #20).
    f16x8 Xa, Xb;                      // A set (f16 mode), 8 regs
    f32x4 F0, F1, F2, F3;              // A set (f32 mode), 16 regs
    f32x4 M0a,M0b,R0a,R0b,E0a,E0b;     // W set0, 24 regs
    f32x4 M1a,M1b,R1a,R1b,E1a,E1b;     // W set1, 24 regs

    // Prologue.
    if (isA) { ISSUE_A(0); }
    else {
        ISSUE_W(0, M0a,M0b,R0a,R0b,E0a,E0b);
        ISSUE_W(1, M1a,M1b,R1a,R1b,E1a,E1b);
    }
    if (isA) { COMMIT_A(0); ISSUE_A(1); }
    else     { COMMIT_W(0, M0a,M0b,R0a,R0b,E0a,E0b); }
    BARRIER();

    for (int s = 0; s < NSTEP; s += 2) {
        // even: compute buf0 (k=s); commit k=s+1 -> buf1; prefetch ahead.
        if (!isA && s + 2 < NSTEP) ISSUE_W(s + 2, M0a,M0b,R0a,R0b,E0a,E0b);
        MSTEP(0);
        if (isA) { COMMIT_A(1); if (s + 2 < NSTEP) ISSUE_A(s + 2); }
        else     { COMMIT_W(1, M1a,M1b,R1a,R1b,E1a,E1b); }
        BARRIER();
        // odd: compute buf1 (k=s+1); commit k=s+2 -> buf0; prefetch ahead.
        if (!isA && s + 3 < NSTEP) ISSUE_W(s + 3, M1a,M1b,R1a,R1b,E1a,E1b);
        MSTEP(1);
        if (s + 2 < NSTEP) {
            if (isA) { COMMIT_A(0); ISSUE_A(s + 3 < NSTEP ? s + 3 : NSTEP - 1); }
            else     { COMMIT_W(0, M0a,M0b,R0a,R0b,E0a,E0b); }
        }
        BARRIER();
    }

    // Epilogue: bias (k-split 0 only), one f32 atomicAdd per element per split.
    float bias[2] = {0.f, 0.f};
    if (sk == 0) {
#pragma unroll
        for (int j = 0; j < 2; ++j) {
            const int c = n_base + wn * 32 + j * 16 + (lane & 15);
            bias[j] = mub[c] + softplus_f(rhob[c]) * epsb[c];
        }
    }
#pragma unroll
    for (int i = 0; i < 4; ++i) {
        const int r = wm * 64 + i * 16 + ((lane >> 4) << 2);
#pragma unroll
        for (int j = 0; j < 2; ++j) {
            const int c = n_base + wn * 32 + j * 16 + (lane & 15);
            float* po = out + (size_t)r * OUT_DIM + c;
#pragma unroll
            for (int q = 0; q < 4; ++q)
                atomicAdd(po + (size_t)q * OUT_DIM, acc[i][j][q] + bias[j]);
        }
    }
}

// Pre-pass: x (f32, 2M elems) -> f16 in d_ws. ~3 us, graph-capture safe.
__global__ void cvt_x16(const float* __restrict__ x, f16* __restrict__ x16) {
    const int i = (blockIdx.x * 256 + threadIdx.x) * 4;
    const f32x4 v = *(const f32x4*)(x + i);
    f16 o[4];
#pragma unroll
    for (int q = 0; q < 4; ++q) o[q] = (f16)v[q];
    *(unsigned long long*)(x16 + i) = *(unsigned long long*)o;
}

extern "C" void kernel_launch(void* const* d_in, const int* in_sizes, int n_in,
                              void* d_out, int out_size, void* d_ws, size_t ws_size,
                              hipStream_t stream) {
    (void)in_sizes; (void)n_in;
    const float* x    = (const float*)d_in[0];
    const float* muw  = (const float*)d_in[1];
    const float* rhow = (const float*)d_in[2];
    const float* mub  = (const float*)d_in[3];
    const float* rhob = (const float*)d_in[4];
    const float* epsw = (const float*)d_in[5];
    const float* epsb = (const float*)d_in[6];
    float* out = (float*)d_out;

    hipMemsetAsync(out, 0, (size_t)out_size * sizeof(float), stream);

    const size_t xelems = (size_t)BATCH * IN_DIM;
    if (ws_size >= xelems * sizeof(f16)) {
        f16* x16 = (f16*)d_ws;
        cvt_x16<<<dim3(xelems / 1024), dim3(256), 0, stream>>>(x, x16);
        vl_main<true><<<dim3(256), dim3(1024), 0, stream>>>(
            x, x16, muw, rhow, epsw, mub, rhob, epsb, out);
    } else {
        vl_main<false><<<dim3(256), dim3(1024), 0, stream>>>(
            x, nullptr, muw, rhow, epsw, mub, rhob, epsb, out);
    }
}